// Round 6
// baseline (437.039 us; speedup 1.0000x reference)
//
#include <hip/hip_runtime.h>
#include <cstdint>
#include <cstddef>

typedef _Float16 f16;
typedef __attribute__((ext_vector_type(4))) _Float16 f16x4;
typedef __attribute__((ext_vector_type(8))) _Float16 f16x8;
typedef __attribute__((ext_vector_type(4))) float f32x4;

#define MFMA_F16(a, b, c) __builtin_amdgcn_mfma_f32_16x16x32_f16((a), (b), (c), 0, 0, 0)

static constexpr int BB   = 8;
static constexpr int SS   = 2048;
static constexpr int DD   = 1024;
static constexpr int HALF = 512;
static constexpr int T32  = 256 * 32;   // f16 elems per K-tile slot (16 KB)

// async global->LDS, 16 B per lane; LDS dest is wave-uniform base + lane*16.
__device__ __forceinline__ void gll16(const f16* g, f16* lds) {
  __builtin_amdgcn_global_load_lds(
      (__attribute__((address_space(1))) void*)(g),
      (__attribute__((address_space(3))) void*)(lds), 16, 0, 0);
}

// Bijective XCD-aware block remap (valid when nwg % 8 == 0).  Used ONLY for
// qk/pv, where z-chunking gives each XCD one batch -> K/Vt panels L2-resident.
// NOT for proj: natural order already co-locates all 12 consumers of an
// A-tile on one XCD (lin = x + 64y + 256z, 64 == 0 mod 8).
__device__ __forceinline__ dim3 xcd_swz() {
  const int gx = gridDim.x, gy = gridDim.y;
  const int lin = blockIdx.x + gx * (blockIdx.y + gy * blockIdx.z);
  const int nwg = gx * gy * (int)gridDim.z;
  const int q = nwg >> 3;
  const int nlin = (lin & 7) * q + (lin >> 3);
  dim3 r;
  r.x = nlin % gx;
  const int rest = nlin / gx;
  r.y = rest % gy;
  r.z = rest / gy;
  return r;
}

// ---------------------------------------------------------------------------
// Fused prep: blocks [0,1024) convert W (fp32->fp16); blocks [1024,1024+16384)
// build Xh = concat(t_out,c_out) fp16 for ALL 8 batches.
// ---------------------------------------------------------------------------
__global__ __launch_bounds__(256) void fused_prep(
    const float* __restrict__ Wq, const float* __restrict__ Wk, const float* __restrict__ Wv,
    const float* __restrict__ t_out, const float* __restrict__ c_out,
    f16* __restrict__ Whq, f16* __restrict__ Whk, f16* __restrict__ Whv,
    f16* __restrict__ Xh)
{
  if (blockIdx.x < 1024) {
    const int i = (blockIdx.x * 256 + threadIdx.x) * 4;
    const float4 q = *(const float4*)(Wq + i);
    const float4 k = *(const float4*)(Wk + i);
    const float4 v = *(const float4*)(Wv + i);
    f16x4 a;
    a.x = (f16)q.x; a.y = (f16)q.y; a.z = (f16)q.z; a.w = (f16)q.w; *(f16x4*)(Whq + i) = a;
    a.x = (f16)k.x; a.y = (f16)k.y; a.z = (f16)k.z; a.w = (f16)k.w; *(f16x4*)(Whk + i) = a;
    a.x = (f16)v.x; a.y = (f16)v.y; a.z = (f16)v.z; a.w = (f16)v.w; *(f16x4*)(Whv + i) = a;
  } else {
    const size_t i = ((size_t)(blockIdx.x - 1024) * 256 + threadIdx.x) * 4;
    const int d = (int)(i & 1023);
    const size_t g = i >> 10;  // global token 0..16383
    const float* src = (d < HALF) ? (t_out + g * HALF + d)
                                  : (c_out + g * HALF + (d - HALF));
    const float4 x = *(const float4*)src;
    f16x4 h;
    h.x = (f16)x.x; h.y = (f16)x.y; h.z = (f16)x.z; h.w = (f16)x.w;
    *(f16x4*)(Xh + i) = h;
  }
}

// ---------------------------------------------------------------------------
// 256x256 GEMM, BK=32, 8 waves (512 thr), wave C = 128x64.
// LDS: ring of 4 K-tile slots per operand ([256][32] f16, 16 KB) = 128 KiB.
// Swizzle: 16B granule g of row r lives at physical granule g ^ ((r>>1)&3);
// applied on the global SOURCE column (LDS dest linear) and on the ds_read
// address (both-sides rule).  Proven conflict-free (R1-R5: SQ_LDS_BANK_CONFLICT=0).
//
// R6: register READ-AHEAD by one phase (R5 post-mortem: phases serialized
// {LDS drain 770cy} -> {MFMA 155cy}; m201 overlaps them).  Frags consumed by
// a phase's MFMA are issued one phase EARLIER; the compiler's own counted
// lgkmcnt lets the just-issued reads drain under the MFMA cluster.
//   p0(t): issue a_hi[t]      (4 rd); MFMA a_lo[t] x b_cur
//   p1(t): issue b[t+1],a_lo[t+1] (8 rd); MFMA a_hi[t] x b_cur
// b double-buffered via 2x-unrolled tile loop (static reg names).
// Safety: tile t+1 is CERTIFIED at t's p0 vmcnt (ledger certifies one tile
// early), so p1's cross-tile pre-reads are race-free.  WAR: stagers write
// slot (t+3)&3, readers touch (t)&3 and (t+1)&3 only.
// vmcnt ledger (4 gll/wave/tile, lead 3): at t p0 after stage, outstanding =
// 10 -> vmcnt(6) retires tile t+1.  Tail: NT-3 -> 4; >=NT-2 -> 0.
// VGPR rule (R4): 512-thr -> 2 waves/SIMD -> 256 cap; acc128+frags64 fits.
// ---------------------------------------------------------------------------
__device__ __forceinline__ void stage_half(
    f16* s, const f16* g, size_t r0, int ld, int k0, int u, int w4, int rr, int gg)
{
#pragma unroll
  for (int q = 0; q < 2; ++q) {
    const int rb  = u * 128 + w4 * 32 + q * 16;   // wave-uniform row block
    const int row = rb + rr;
    const int lg  = gg ^ ((row >> 1) & 3);        // pre-swizzled source granule
    gll16(g + (r0 + (size_t)row) * ld + k0 + lg * 8, s + (size_t)rb * 32);
  }
}

template <int NT>
__device__ __forceinline__ void tile_body(
    int t, const f16* As, const f16* Bs, f16* ring,
    const f16* g_st, size_t r0_st, int ld_st,
    f32x4 acc[8][4], f16x8 (&bc)[4], f16x8 (&bn)[4],
    f16x8 (&alo)[4], f16x8 (&ahi)[4],
    int w4, int rr, int gg, int wm, int wn, int col16, int quad)
{
  const f16* At  = As + (t & 3) * T32;
  const f16* Atn = As + ((t + 1) & 3) * T32;
  const f16* Btn = Bs + ((t + 1) & 3) * T32;
  f16* Sn = ring + ((t + 3) & 3) * T32;
  const bool st = (t + 3 < NT);
  const int kn = (t + 3) * 32;

  // ---- p0: issue a_hi[t] (for p1); MFMA a_lo[t] x b_cur ------------------
#pragma unroll
  for (int i = 0; i < 4; ++i) {
    const int r = wm * 128 + 64 + i * 16 + col16;
    ahi[i] = *(const f16x8*)&At[r * 32 + ((quad ^ ((r >> 1) & 3)) << 3)];
  }
  if (st) stage_half(Sn, g_st, r0_st, ld_st, kn, 0, w4, rr, gg);
  if (t < NT - 3)       asm volatile("s_waitcnt vmcnt(6)" ::: "memory");
  else if (t == NT - 3) asm volatile("s_waitcnt vmcnt(4)" ::: "memory");
  else                  asm volatile("s_waitcnt vmcnt(0)" ::: "memory");
  __builtin_amdgcn_sched_barrier(0);
  __builtin_amdgcn_s_barrier();
  __builtin_amdgcn_s_setprio(1);
#pragma unroll
  for (int i = 0; i < 4; ++i)
#pragma unroll
    for (int j = 0; j < 4; ++j)
      acc[i][j] = MFMA_F16(alo[i], bc[j], acc[i][j]);
  __builtin_amdgcn_s_setprio(0);
  __builtin_amdgcn_s_barrier();

  // ---- p1: issue b[t+1], a_lo[t+1]; MFMA a_hi[t] x b_cur -----------------
  if (t + 1 < NT) {
#pragma unroll
    for (int j = 0; j < 4; ++j) {
      const int r = wn * 64 + j * 16 + col16;
      bn[j] = *(const f16x8*)&Btn[r * 32 + ((quad ^ ((r >> 1) & 3)) << 3)];
    }
#pragma unroll
    for (int i = 0; i < 4; ++i) {
      const int r = wm * 128 + i * 16 + col16;
      alo[i] = *(const f16x8*)&Atn[r * 32 + ((quad ^ ((r >> 1) & 3)) << 3)];
    }
  }
  if (st) stage_half(Sn, g_st, r0_st, ld_st, kn, 1, w4, rr, gg);
  __builtin_amdgcn_sched_barrier(0);
  __builtin_amdgcn_s_barrier();
  __builtin_amdgcn_s_setprio(1);
#pragma unroll
  for (int i = 0; i < 4; ++i)
#pragma unroll
    for (int j = 0; j < 4; ++j)
      acc[i + 4][j] = MFMA_F16(ahi[i], bc[j], acc[i + 4][j]);
  __builtin_amdgcn_s_setprio(0);
  __builtin_amdgcn_s_barrier();
}

template <int K>
__device__ __forceinline__ void mma_pipeline(
    const f16* __restrict__ A, const f16* __restrict__ B,
    int lda, int ldb, size_t arow0, size_t brow0,
    f16* As, f16* Bs, f32x4 acc[8][4],
    int wave, int lane, int wm, int wn, int col16, int quad)
{
  constexpr int NT = K / 32;           // 32 or 64 (even, >= 4)
  const int w4 = wave & 3, rr = lane >> 2, gg = lane & 3;
  const f16*  g_st  = (wave < 4) ? A : B;
  const size_t r0_st = (wave < 4) ? arow0 : brow0;
  const int    ld_st = (wave < 4) ? lda : ldb;
  f16*         ring  = (wave < 4) ? As : Bs;

  // prologue: stage tiles 0,1,2 (12 gll/wave); certify tile 0.
#pragma unroll
  for (int pt = 0; pt < 3; ++pt)
#pragma unroll
    for (int u = 0; u < 2; ++u)
      stage_half(ring + pt * T32, g_st, r0_st, ld_st, pt * 32, u, w4, rr, gg);
  asm volatile("s_waitcnt vmcnt(8)" ::: "memory");
  __builtin_amdgcn_s_barrier();

  // preload tile 0 fragments: b_cur (bA) and a_lo.
  f16x8 bA[4], bB[4], alo[4], ahi[4];
#pragma unroll
  for (int j = 0; j < 4; ++j) {
    const int r = wn * 64 + j * 16 + col16;
    bA[j] = *(const f16x8*)&Bs[r * 32 + ((quad ^ ((r >> 1) & 3)) << 3)];
  }
#pragma unroll
  for (int i = 0; i < 4; ++i) {
    const int r = wm * 128 + i * 16 + col16;
    alo[i] = *(const f16x8*)&As[r * 32 + ((quad ^ ((r >> 1) & 3)) << 3)];
  }

  for (int tt = 0; tt < NT; tt += 2) {
    tile_body<NT>(tt,     As, Bs, ring, g_st, r0_st, ld_st, acc, bA, bB,
                  alo, ahi, w4, rr, gg, wm, wn, col16, quad);
    tile_body<NT>(tt + 1, As, Bs, ring, g_st, r0_st, ld_st, acc, bB, bA,
                  alo, ahi, w4, rr, gg, wm, wn, col16, quad);
  }
}

// ---------------------------------------------------------------------------
// QKV projection. grid (64, 4, 3): x = m-tile, y = n-tile, z = Q/K/V.
// NATURAL block order (see xcd_swz comment).
// ---------------------------------------------------------------------------
__global__ __launch_bounds__(512, 2) void proj_gemm(
    const f16* __restrict__ Xh,
    const f16* __restrict__ Whq, const f16* __restrict__ Whk, const f16* __restrict__ Whv,
    const float* __restrict__ bq, const float* __restrict__ bk, const float* __restrict__ bv,
    f16* __restrict__ Q, f16* __restrict__ K, f16* __restrict__ Vv)
{
  __shared__ alignas(16) f16 As[4 * T32];
  __shared__ alignas(16) f16 Bs[4 * T32];

  const int z = blockIdx.z;
  const f16* Wh = (z == 0) ? Whq : (z == 1) ? Whk : Whv;
  const float* bias = (z == 0) ? bq : (z == 1) ? bk : bv;
  f16* dst = (z == 0) ? Q : (z == 1) ? K : Vv;

  const int t = threadIdx.x, lane = t & 63, wave = t >> 6;
  const int wm = wave >> 2, wn = wave & 3, col16 = lane & 15, quad = lane >> 4;
  const int m0 = blockIdx.x * 256, n0 = blockIdx.y * 256;

  f32x4 acc[8][4];
#pragma unroll
  for (int i = 0; i < 8; ++i)
#pragma unroll
    for (int j = 0; j < 4; ++j) acc[i][j] = f32x4{0.f, 0.f, 0.f, 0.f};

  mma_pipeline<DD>(Xh, Wh, DD, DD, (size_t)m0, (size_t)n0,
                   As, Bs, acc, wave, lane, wm, wn, col16, quad);

#pragma unroll
  for (int j = 0; j < 4; ++j) {
    const int gn = n0 + wn * 64 + j * 16 + col16;
    const float bb_ = bias[gn];
#pragma unroll
    for (int i = 0; i < 8; ++i) {
      const int gm = m0 + wm * 128 + i * 16 + quad * 4;
#pragma unroll
      for (int r = 0; r < 4; ++r)
        dst[(size_t)(gm + r) * DD + gn] = (f16)(acc[i][j][r] + bb_);
    }
  }
}

// ---------------------------------------------------------------------------
// Transpose V [b][s][e] -> Vt [b][e][s], full batch (grid 32,16,8)
// ---------------------------------------------------------------------------
__global__ __launch_bounds__(256) void transpose_v(
    const f16* __restrict__ Vv, f16* __restrict__ Vt)
{
  __shared__ alignas(16) f16 tile[64][72];
  const int b  = blockIdx.z;
  const int s0 = blockIdx.x * 64;
  const int e0 = blockIdx.y * 64;
  const int t  = threadIdx.x;
  const int r  = t >> 3;
  const int c8 = (t & 7) * 8;

  const f16* src0 = Vv + ((size_t)(b * SS + s0 + r)) * DD + e0 + c8;
  const f16* src1 = Vv + ((size_t)(b * SS + s0 + r + 32)) * DD + e0 + c8;
  *(int4*)&tile[r][c8]      = *(const int4*)src0;
  *(int4*)&tile[r + 32][c8] = *(const int4*)src1;
  __syncthreads();

  f16x8 v0, v1;
#pragma unroll
  for (int u = 0; u < 8; ++u) {
    v0[u] = tile[c8 + u][r];
    v1[u] = tile[c8 + u][r + 32];
  }
  f16* dst0 = Vt + ((size_t)b * DD + e0 + r) * SS + s0 + c8;
  f16* dst1 = Vt + ((size_t)b * DD + e0 + r + 32) * SS + s0 + c8;
  *(f16x8*)dst0 = v0;
  *(f16x8*)dst1 = v1;
}

// ---------------------------------------------------------------------------
// Scores for chunk [b0, b0+c): grid (8, 8, c), 256x256 tiles.
// ---------------------------------------------------------------------------
__global__ __launch_bounds__(512, 2) void qk_gemm(
    const f16* __restrict__ Q, const f16* __restrict__ K, f16* __restrict__ Sc,
    int b0)
{
  __shared__ alignas(16) f16 As[4 * T32];
  __shared__ alignas(16) f16 Bs[4 * T32];

  const dim3 bid = xcd_swz();
  const int bb = bid.z;
  const int t = threadIdx.x, lane = t & 63, wave = t >> 6;
  const int wm = wave >> 2, wn = wave & 3, col16 = lane & 15, quad = lane >> 4;
  const int m0 = bid.y * 256, n0 = bid.x * 256;

  const size_t arow0 = (size_t)(b0 + bb) * SS + m0;
  const size_t brow0 = (size_t)(b0 + bb) * SS + n0;

  f32x4 acc[8][4];
#pragma unroll
  for (int i = 0; i < 8; ++i)
#pragma unroll
    for (int j = 0; j < 4; ++j) acc[i][j] = f32x4{0.f, 0.f, 0.f, 0.f};

  mma_pipeline<DD>(Q, K, DD, DD, arow0, brow0,
                   As, Bs, acc, wave, lane, wm, wn, col16, quad);

#pragma unroll
  for (int i = 0; i < 8; ++i)
#pragma unroll
    for (int j = 0; j < 4; ++j)
#pragma unroll
      for (int r = 0; r < 4; ++r) {
        const int gm = m0 + wm * 128 + i * 16 + quad * 4 + r;
        const int gn = n0 + wn * 64 + j * 16 + col16;
        Sc[((size_t)bb * SS + gm) * SS + gn] = (f16)acc[i][j][r];
      }
}

// ---------------------------------------------------------------------------
// Row softmax fp16 -> fp16, in place (row = 2048 f16; 256 thr x f16x8).
// ---------------------------------------------------------------------------
__global__ __launch_bounds__(256) void softmax_rows(f16* __restrict__ Sc)
{
  const size_t row = blockIdx.x;
  f16* p = Sc + row * SS;
  const int t = threadIdx.x;

  const f16x8 v = *(const f16x8*)(p + t * 8);
  float xs[8];
#pragma unroll
  for (int u = 0; u < 8; ++u) xs[u] = (float)v[u];

  float m = xs[0];
#pragma unroll
  for (int u = 1; u < 8; ++u) m = fmaxf(m, xs[u]);
#pragma unroll
  for (int off = 32; off > 0; off >>= 1) m = fmaxf(m, __shfl_xor(m, off));
  __shared__ float redm[4];
  __shared__ float reds[4];
  if ((t & 63) == 0) redm[t >> 6] = m;
  __syncthreads();
  m = fmaxf(fmaxf(redm[0], redm[1]), fmaxf(redm[2], redm[3]));

  float e[8];
  float s = 0.f;
#pragma unroll
  for (int u = 0; u < 8; ++u) {
    e[u] = expf(xs[u] - m);
    s += e[u];
  }
#pragma unroll
  for (int off = 32; off > 0; off >>= 1) s += __shfl_xor(s, off);
  if ((t & 63) == 0) reds[t >> 6] = s;
  __syncthreads();
  s = reds[0] + reds[1] + reds[2] + reds[3];
  const float inv = 1.0f / s;

  f16x8 o;
#pragma unroll
  for (int u = 0; u < 8; ++u) o[u] = (f16)(e[u] * inv);
  *(f16x8*)(p + t * 8) = o;
}

// ---------------------------------------------------------------------------
// Output: out[(b0+bb)][s][e] = sum_j P[bb][s][j] * Vt[b0+bb][e][j]
// grid (4, 8, c), 256x256 tiles, K = SS = 2048.
// ---------------------------------------------------------------------------
__global__ __launch_bounds__(512, 2) void pv_gemm(
    const f16* __restrict__ P, const f16* __restrict__ Vt, float* __restrict__ out,
    int b0)
{
  __shared__ alignas(16) f16 As[4 * T32];
  __shared__ alignas(16) f16 Bs[4 * T32];

  const dim3 bid = xcd_swz();
  const int bb = bid.z;
  const int t = threadIdx.x, lane = t & 63, wave = t >> 6;
  const int wm = wave >> 2, wn = wave & 3, col16 = lane & 15, quad = lane >> 4;
  const int m0 = bid.y * 256;  // s
  const int n0 = bid.x * 256;  // e

  const size_t arow0 = (size_t)bb * SS + m0;         // P rows (pitch SS)
  const size_t brow0 = (size_t)(b0 + bb) * DD + n0;  // Vt rows (pitch SS)

  f32x4 acc[8][4];
#pragma unroll
  for (int i = 0; i < 8; ++i)
#pragma unroll
    for (int j = 0; j < 4; ++j) acc[i][j] = f32x4{0.f, 0.f, 0.f, 0.f};

  mma_pipeline<SS>(P, Vt, SS, SS, arow0, brow0,
                   As, Bs, acc, wave, lane, wm, wn, col16, quad);

#pragma unroll
  for (int i = 0; i < 8; ++i)
#pragma unroll
    for (int j = 0; j < 4; ++j)
#pragma unroll
      for (int r = 0; r < 4; ++r) {
        const int gm = m0 + wm * 128 + i * 16 + quad * 4 + r;
        const int gn = n0 + wn * 64 + j * 16 + col16;
        out[((size_t)(b0 + bb) * SS + gm) * DD + gn] = acc[i][j][r];
      }
}

// ---------------------------------------------------------------------------
extern "C" void kernel_launch(void* const* d_in, const int* in_sizes, int n_in,
                              void* d_out, int out_size, void* d_ws, size_t ws_size,
                              hipStream_t stream)
{
  const float* t_out = (const float*)d_in[0];
  const float* c_out = (const float*)d_in[1];
  const float* Wq    = (const float*)d_in[2];
  const float* bq    = (const float*)d_in[3];
  const float* Wk    = (const float*)d_in[4];
  const float* bk    = (const float*)d_in[5];
  const float* Wv    = (const float*)d_in[6];
  const float* bv    = (const float*)d_in[7];
  float* out = (float*)d_out;

  // ---- sizes ----
  const size_t WELT  = (size_t)DD * DD;
  const size_t TD8   = (size_t)BB * SS * DD;             // 16.7M elems
  const size_t XH_B  = TD8 * sizeof(f16);                // 33.55 MB
  const size_t SC1_B = (size_t)SS * SS * sizeof(f16);    // 8.39 MB per batch

  // ---- pick Sc chunk c (pure function of ws_size -> graph-safe) ----
  const size_t FIXED = 3 * WELT * sizeof(f16) + 4 * XH_B;  // 140.5 MB
  int c = 2;
  for (int cand : {8, 4}) {
    size_t xsc = (size_t)cand * SC1_B;
    if (xsc < XH_B) xsc = XH_B;
    if (FIXED + xsc <= ws_size) { c = cand; break; }
  }
  size_t xsc_bytes = (size_t)c * SC1_B;
  if (xsc_bytes < XH_B) xsc_bytes = XH_B;

  // ---- layout: [W][Xh|Sc(alias)][Q][K][Vv][Vt] ----
  char* ws = (char*)d_ws;
  f16* Whq = (f16*)ws;
  f16* Whk = Whq + WELT;
  f16* Whv = Whk + WELT;
  char* XSc = (char*)(Whv + WELT);
  f16* Xh = (f16*)XSc;     // live during prep/proj
  f16* Sc = (f16*)XSc;     // live during attention chunks (aliases Xh)
  f16* Q  = (f16*)(XSc + xsc_bytes);
  f16* K  = Q  + TD8;
  f16* Vv = K  + TD8;
  f16* Vt = Vv + TD8;

  fused_prep<<<dim3(1024 + 16384), dim3(256), 0, stream>>>(
      Wq, Wk, Wv, t_out, c_out, Whq, Whk, Whv, Xh);
  proj_gemm<<<dim3(64, 4, 3), dim3(512), 0, stream>>>(
      Xh, Whq, Whk, Whv, bq, bk, bv, Q, K, Vv);
  transpose_v<<<dim3(32, 16, 8), dim3(256), 0, stream>>>(Vv, Vt);

  for (int b0 = 0; b0 < BB; b0 += c) {
    qk_gemm<<<dim3(8, 8, c), dim3(512), 0, stream>>>(Q, K, Sc, b0);
    softmax_rows<<<dim3(c * SS), dim3(256), 0, stream>>>(Sc);
    pv_gemm<<<dim3(4, 8, c), dim3(512), 0, stream>>>(Sc, Vt, out, b0);
  }
}

// Round 7
// 417.407 us; speedup vs baseline: 1.0470x; 1.0470x over previous
//
#include <hip/hip_runtime.h>
#include <cstdint>
#include <cstddef>

typedef _Float16 f16;
typedef __attribute__((ext_vector_type(4))) _Float16 f16x4;
typedef __attribute__((ext_vector_type(8))) _Float16 f16x8;
typedef __attribute__((ext_vector_type(4))) float f32x4;

#define MFMA_F16(a, b, c) __builtin_amdgcn_mfma_f32_16x16x32_f16((a), (b), (c), 0, 0, 0)

static constexpr int BB   = 8;
static constexpr int SS   = 2048;
static constexpr int DD   = 1024;
static constexpr int HALF = 512;
static constexpr int T32  = 256 * 32;   // f16 elems per K-tile slot (16 KB)

// async global->LDS, 16 B per lane; LDS dest is wave-uniform base + lane*16.
__device__ __forceinline__ void gll16(const f16* g, f16* lds) {
  __builtin_amdgcn_global_load_lds(
      (__attribute__((address_space(1))) void*)(g),
      (__attribute__((address_space(3))) void*)(lds), 16, 0, 0);
}

// Bijective XCD-aware block remap (valid when nwg % 8 == 0).  Used ONLY for
// qk/pv, where z-chunking gives each XCD one batch -> K/Vt panels L2-resident.
// NOT for proj: natural order already co-locates all 12 consumers of an
// A-tile on one XCD (lin = x + 64y + 256z, 64 == 0 mod 8).
__device__ __forceinline__ dim3 xcd_swz() {
  const int gx = gridDim.x, gy = gridDim.y;
  const int lin = blockIdx.x + gx * (blockIdx.y + gy * blockIdx.z);
  const int nwg = gx * gy * (int)gridDim.z;
  const int q = nwg >> 3;
  const int nlin = (lin & 7) * q + (lin >> 3);
  dim3 r;
  r.x = nlin % gx;
  const int rest = nlin / gx;
  r.y = rest % gy;
  r.z = rest / gy;
  return r;
}

// ---------------------------------------------------------------------------
// Fused prep: blocks [0,1024) convert W (fp32->fp16); blocks [1024,1024+16384)
// build Xh = concat(t_out,c_out) fp16 for ALL 8 batches.
// ---------------------------------------------------------------------------
__global__ __launch_bounds__(256) void fused_prep(
    const float* __restrict__ Wq, const float* __restrict__ Wk, const float* __restrict__ Wv,
    const float* __restrict__ t_out, const float* __restrict__ c_out,
    f16* __restrict__ Whq, f16* __restrict__ Whk, f16* __restrict__ Whv,
    f16* __restrict__ Xh)
{
  if (blockIdx.x < 1024) {
    const int i = (blockIdx.x * 256 + threadIdx.x) * 4;
    const float4 q = *(const float4*)(Wq + i);
    const float4 k = *(const float4*)(Wk + i);
    const float4 v = *(const float4*)(Wv + i);
    f16x4 a;
    a.x = (f16)q.x; a.y = (f16)q.y; a.z = (f16)q.z; a.w = (f16)q.w; *(f16x4*)(Whq + i) = a;
    a.x = (f16)k.x; a.y = (f16)k.y; a.z = (f16)k.z; a.w = (f16)k.w; *(f16x4*)(Whk + i) = a;
    a.x = (f16)v.x; a.y = (f16)v.y; a.z = (f16)v.z; a.w = (f16)v.w; *(f16x4*)(Whv + i) = a;
  } else {
    const size_t i = ((size_t)(blockIdx.x - 1024) * 256 + threadIdx.x) * 4;
    const int d = (int)(i & 1023);
    const size_t g = i >> 10;  // global token 0..16383
    const float* src = (d < HALF) ? (t_out + g * HALF + d)
                                  : (c_out + g * HALF + (d - HALF));
    const float4 x = *(const float4*)src;
    f16x4 h;
    h.x = (f16)x.x; h.y = (f16)x.y; h.z = (f16)x.z; h.w = (f16)x.w;
    *(f16x4*)(Xh + i) = h;
  }
}

// ---------------------------------------------------------------------------
// 256x256 GEMM, BK=32, 8 waves (512 thr), wave C = 128x64.
// LDS: ring of 4 K-tile slots per operand ([256][32] f16, 16 KB) = 128 KiB.
// Swizzle: granule g of row r at physical granule g ^ ((r>>1)&3); applied on
// the global SOURCE column (LDS dest linear) and the ds_read address.
// Proven conflict-free (R1-R6: SQ_LDS_BANK_CONFLICT = 0).
//
// R7: ONE barrier per K-tile (R6 post-mortem: MFMA-work and LDS-work are
// each ~40% of wall; 4 barriers/tile lockstepped the 2 waves/SIMD so they
// contended instead of overlapping).  With R6's read-ahead, all intra-tile
// barriers carry no data dep; waves may drift up to a tile and overlap
// read-burst with MFMA-burst.  setprio arbitrates.
//   tile t: { issue ahi[t] (4 rd); vmcnt; s_barrier; sched_barrier;
//             stage h0 -> slot t+3; MFMA alo[t] x bc (16);
//             issue b[t+1], alo[t+1] (8 rd); stage h1; MFMA ahi[t] x bc (16) }
// RAW: slot t+1 reads sit after tile t's barrier; vmcnt(4) there retires
//   tile t+1's 4 stages/wave (outstanding = 8: tiles t+1,t+2).  Tail:
//   t==NT-2 -> vmcnt(0); t==NT-1 no pre-reads, no wait.
// WAR: stage->slot (t+3)&3 == (t-1)&3 issued AFTER the entry barrier; every
//   wave passed it only after its t-1 MFMAs consumed slot t-1 (lgkmcnt).
// VGPR rule (R4): 512-thr -> 2 waves/SIMD -> 256 cap; acc128 + frags fits.
// ---------------------------------------------------------------------------
__device__ __forceinline__ void stage_half(
    f16* s, const f16* g, size_t r0, int ld, int k0, int u, int w4, int rr, int gg)
{
#pragma unroll
  for (int q = 0; q < 2; ++q) {
    const int rb  = u * 128 + w4 * 32 + q * 16;   // wave-uniform row block
    const int row = rb + rr;
    const int lg  = gg ^ ((row >> 1) & 3);        // pre-swizzled source granule
    gll16(g + (r0 + (size_t)row) * ld + k0 + lg * 8, s + (size_t)rb * 32);
  }
}

template <int NT>
__device__ __forceinline__ void tile_body(
    int t, const f16* As, const f16* Bs, f16* ring,
    const f16* g_st, size_t r0_st, int ld_st,
    f32x4 acc[8][4], f16x8 (&bc)[4], f16x8 (&bn)[4],
    f16x8 (&alo)[4], f16x8 (&ahi)[4],
    int w4, int rr, int gg, int wm, int wn, int col16, int quad)
{
  const f16* At  = As + (t & 3) * T32;
  const f16* Atn = As + ((t + 1) & 3) * T32;
  const f16* Btn = Bs + ((t + 1) & 3) * T32;
  f16* Sn = ring + ((t + 3) & 3) * T32;
  const bool st = (t + 3 < NT);
  const int kn = (t + 3) * 32;

  // issue a_hi[t] reads (slot t certified at t-1's barrier); overlap barrier.
#pragma unroll
  for (int i = 0; i < 4; ++i) {
    const int r = wm * 128 + 64 + i * 16 + col16;
    ahi[i] = *(const f16x8*)&At[r * 32 + ((quad ^ ((r >> 1) & 3)) << 3)];
  }
  // certify slot t+1 for this tile's pre-reads, then the ONE tile barrier.
  if (t < NT - 2)       asm volatile("s_waitcnt vmcnt(4)" ::: "memory");
  else if (t == NT - 2) asm volatile("s_waitcnt vmcnt(0)" ::: "memory");
  __builtin_amdgcn_s_barrier();
  __builtin_amdgcn_sched_barrier(0);   // nothing crosses the tile boundary

  if (st) stage_half(Sn, g_st, r0_st, ld_st, kn, 0, w4, rr, gg);
  __builtin_amdgcn_s_setprio(1);
#pragma unroll
  for (int i = 0; i < 4; ++i)
#pragma unroll
    for (int j = 0; j < 4; ++j)
      acc[i][j] = MFMA_F16(alo[i], bc[j], acc[i][j]);
  __builtin_amdgcn_s_setprio(0);

  // pre-reads for tile t+1 (slot certified at this tile's vmcnt+barrier)
  if (t + 1 < NT) {
#pragma unroll
    for (int j = 0; j < 4; ++j) {
      const int r = wn * 64 + j * 16 + col16;
      bn[j] = *(const f16x8*)&Btn[r * 32 + ((quad ^ ((r >> 1) & 3)) << 3)];
    }
#pragma unroll
    for (int i = 0; i < 4; ++i) {
      const int r = wm * 128 + i * 16 + col16;
      alo[i] = *(const f16x8*)&Atn[r * 32 + ((quad ^ ((r >> 1) & 3)) << 3)];
    }
  }
  if (st) stage_half(Sn, g_st, r0_st, ld_st, kn, 1, w4, rr, gg);
  __builtin_amdgcn_s_setprio(1);
#pragma unroll
  for (int i = 0; i < 4; ++i)
#pragma unroll
    for (int j = 0; j < 4; ++j)
      acc[i + 4][j] = MFMA_F16(ahi[i], bc[j], acc[i + 4][j]);
  __builtin_amdgcn_s_setprio(0);
}

template <int K>
__device__ __forceinline__ void mma_pipeline(
    const f16* __restrict__ A, const f16* __restrict__ B,
    int lda, int ldb, size_t arow0, size_t brow0,
    f16* As, f16* Bs, f32x4 acc[8][4],
    int wave, int lane, int wm, int wn, int col16, int quad)
{
  constexpr int NT = K / 32;           // 32 or 64 (even, >= 4)
  const int w4 = wave & 3, rr = lane >> 2, gg = lane & 3;
  const f16*  g_st  = (wave < 4) ? A : B;
  const size_t r0_st = (wave < 4) ? arow0 : brow0;
  const int    ld_st = (wave < 4) ? lda : ldb;
  f16*         ring  = (wave < 4) ? As : Bs;

  // prologue: stage tiles 0,1,2 (12 gll/wave); certify tile 0.
#pragma unroll
  for (int pt = 0; pt < 3; ++pt)
#pragma unroll
    for (int u = 0; u < 2; ++u)
      stage_half(ring + pt * T32, g_st, r0_st, ld_st, pt * 32, u, w4, rr, gg);
  asm volatile("s_waitcnt vmcnt(8)" ::: "memory");
  __builtin_amdgcn_s_barrier();

  // preload tile 0 fragments: b_cur (bA) and a_lo.
  f16x8 bA[4], bB[4], alo[4], ahi[4];
#pragma unroll
  for (int j = 0; j < 4; ++j) {
    const int r = wn * 64 + j * 16 + col16;
    bA[j] = *(const f16x8*)&Bs[r * 32 + ((quad ^ ((r >> 1) & 3)) << 3)];
  }
#pragma unroll
  for (int i = 0; i < 4; ++i) {
    const int r = wm * 128 + i * 16 + col16;
    alo[i] = *(const f16x8*)&As[r * 32 + ((quad ^ ((r >> 1) & 3)) << 3)];
  }

  for (int tt = 0; tt < NT; tt += 2) {
    tile_body<NT>(tt,     As, Bs, ring, g_st, r0_st, ld_st, acc, bA, bB,
                  alo, ahi, w4, rr, gg, wm, wn, col16, quad);
    tile_body<NT>(tt + 1, As, Bs, ring, g_st, r0_st, ld_st, acc, bB, bA,
                  alo, ahi, w4, rr, gg, wm, wn, col16, quad);
  }
}

// ---------------------------------------------------------------------------
// QKV projection. grid (64, 4, 3): x = m-tile, y = n-tile, z = Q/K/V.
// NATURAL block order (see xcd_swz comment).
// ---------------------------------------------------------------------------
__global__ __launch_bounds__(512, 2) void proj_gemm(
    const f16* __restrict__ Xh,
    const f16* __restrict__ Whq, const f16* __restrict__ Whk, const f16* __restrict__ Whv,
    const float* __restrict__ bq, const float* __restrict__ bk, const float* __restrict__ bv,
    f16* __restrict__ Q, f16* __restrict__ K, f16* __restrict__ Vv)
{
  __shared__ alignas(16) f16 As[4 * T32];
  __shared__ alignas(16) f16 Bs[4 * T32];

  const int z = blockIdx.z;
  const f16* Wh = (z == 0) ? Whq : (z == 1) ? Whk : Whv;
  const float* bias = (z == 0) ? bq : (z == 1) ? bk : bv;
  f16* dst = (z == 0) ? Q : (z == 1) ? K : Vv;

  const int t = threadIdx.x, lane = t & 63, wave = t >> 6;
  const int wm = wave >> 2, wn = wave & 3, col16 = lane & 15, quad = lane >> 4;
  const int m0 = blockIdx.x * 256, n0 = blockIdx.y * 256;

  f32x4 acc[8][4];
#pragma unroll
  for (int i = 0; i < 8; ++i)
#pragma unroll
    for (int j = 0; j < 4; ++j) acc[i][j] = f32x4{0.f, 0.f, 0.f, 0.f};

  mma_pipeline<DD>(Xh, Wh, DD, DD, (size_t)m0, (size_t)n0,
                   As, Bs, acc, wave, lane, wm, wn, col16, quad);

#pragma unroll
  for (int j = 0; j < 4; ++j) {
    const int gn = n0 + wn * 64 + j * 16 + col16;
    const float bb_ = bias[gn];
#pragma unroll
    for (int i = 0; i < 8; ++i) {
      const int gm = m0 + wm * 128 + i * 16 + quad * 4;
#pragma unroll
      for (int r = 0; r < 4; ++r)
        dst[(size_t)(gm + r) * DD + gn] = (f16)(acc[i][j][r] + bb_);
    }
  }
}

// ---------------------------------------------------------------------------
// Transpose V [b][s][e] -> Vt [b][e][s], full batch (grid 32,16,8)
// ---------------------------------------------------------------------------
__global__ __launch_bounds__(256) void transpose_v(
    const f16* __restrict__ Vv, f16* __restrict__ Vt)
{
  __shared__ alignas(16) f16 tile[64][72];
  const int b  = blockIdx.z;
  const int s0 = blockIdx.x * 64;
  const int e0 = blockIdx.y * 64;
  const int t  = threadIdx.x;
  const int r  = t >> 3;
  const int c8 = (t & 7) * 8;

  const f16* src0 = Vv + ((size_t)(b * SS + s0 + r)) * DD + e0 + c8;
  const f16* src1 = Vv + ((size_t)(b * SS + s0 + r + 32)) * DD + e0 + c8;
  *(int4*)&tile[r][c8]      = *(const int4*)src0;
  *(int4*)&tile[r + 32][c8] = *(const int4*)src1;
  __syncthreads();

  f16x8 v0, v1;
#pragma unroll
  for (int u = 0; u < 8; ++u) {
    v0[u] = tile[c8 + u][r];
    v1[u] = tile[c8 + u][r + 32];
  }
  f16* dst0 = Vt + ((size_t)b * DD + e0 + r) * SS + s0 + c8;
  f16* dst1 = Vt + ((size_t)b * DD + e0 + r + 32) * SS + s0 + c8;
  *(f16x8*)dst0 = v0;
  *(f16x8*)dst1 = v1;
}

// ---------------------------------------------------------------------------
// Scores for chunk [b0, b0+c): grid (8, 8, c), 256x256 tiles.
// ---------------------------------------------------------------------------
__global__ __launch_bounds__(512, 2) void qk_gemm(
    const f16* __restrict__ Q, const f16* __restrict__ K, f16* __restrict__ Sc,
    int b0)
{
  __shared__ alignas(16) f16 As[4 * T32];
  __shared__ alignas(16) f16 Bs[4 * T32];

  const dim3 bid = xcd_swz();
  const int bb = bid.z;
  const int t = threadIdx.x, lane = t & 63, wave = t >> 6;
  const int wm = wave >> 2, wn = wave & 3, col16 = lane & 15, quad = lane >> 4;
  const int m0 = bid.y * 256, n0 = bid.x * 256;

  const size_t arow0 = (size_t)(b0 + bb) * SS + m0;
  const size_t brow0 = (size_t)(b0 + bb) * SS + n0;

  f32x4 acc[8][4];
#pragma unroll
  for (int i = 0; i < 8; ++i)
#pragma unroll
    for (int j = 0; j < 4; ++j) acc[i][j] = f32x4{0.f, 0.f, 0.f, 0.f};

  mma_pipeline<DD>(Q, K, DD, DD, arow0, brow0,
                   As, Bs, acc, wave, lane, wm, wn, col16, quad);

#pragma unroll
  for (int i = 0; i < 8; ++i)
#pragma unroll
    for (int j = 0; j < 4; ++j)
#pragma unroll
      for (int r = 0; r < 4; ++r) {
        const int gm = m0 + wm * 128 + i * 16 + quad * 4 + r;
        const int gn = n0 + wn * 64 + j * 16 + col16;
        Sc[((size_t)bb * SS + gm) * SS + gn] = (f16)acc[i][j][r];
      }
}

// ---------------------------------------------------------------------------
// Row softmax fp16 -> fp16, in place (row = 2048 f16; 256 thr x f16x8).
// ---------------------------------------------------------------------------
__global__ __launch_bounds__(256) void softmax_rows(f16* __restrict__ Sc)
{
  const size_t row = blockIdx.x;
  f16* p = Sc + row * SS;
  const int t = threadIdx.x;

  const f16x8 v = *(const f16x8*)(p + t * 8);
  float xs[8];
#pragma unroll
  for (int u = 0; u < 8; ++u) xs[u] = (float)v[u];

  float m = xs[0];
#pragma unroll
  for (int u = 1; u < 8; ++u) m = fmaxf(m, xs[u]);
#pragma unroll
  for (int off = 32; off > 0; off >>= 1) m = fmaxf(m, __shfl_xor(m, off));
  __shared__ float redm[4];
  __shared__ float reds[4];
  if ((t & 63) == 0) redm[t >> 6] = m;
  __syncthreads();
  m = fmaxf(fmaxf(redm[0], redm[1]), fmaxf(redm[2], redm[3]));

  float e[8];
  float s = 0.f;
#pragma unroll
  for (int u = 0; u < 8; ++u) {
    e[u] = expf(xs[u] - m);
    s += e[u];
  }
#pragma unroll
  for (int off = 32; off > 0; off >>= 1) s += __shfl_xor(s, off);
  if ((t & 63) == 0) reds[t >> 6] = s;
  __syncthreads();
  s = reds[0] + reds[1] + reds[2] + reds[3];
  const float inv = 1.0f / s;

  f16x8 o;
#pragma unroll
  for (int u = 0; u < 8; ++u) o[u] = (f16)(e[u] * inv);
  *(f16x8*)(p + t * 8) = o;
}

// ---------------------------------------------------------------------------
// Output: out[(b0+bb)][s][e] = sum_j P[bb][s][j] * Vt[b0+bb][e][j]
// grid (4, 8, c), 256x256 tiles, K = SS = 2048.
// ---------------------------------------------------------------------------
__global__ __launch_bounds__(512, 2) void pv_gemm(
    const f16* __restrict__ P, const f16* __restrict__ Vt, float* __restrict__ out,
    int b0)
{
  __shared__ alignas(16) f16 As[4 * T32];
  __shared__ alignas(16) f16 Bs[4 * T32];

  const dim3 bid = xcd_swz();
  const int bb = bid.z;
  const int t = threadIdx.x, lane = t & 63, wave = t >> 6;
  const int wm = wave >> 2, wn = wave & 3, col16 = lane & 15, quad = lane >> 4;
  const int m0 = bid.y * 256;  // s
  const int n0 = bid.x * 256;  // e

  const size_t arow0 = (size_t)bb * SS + m0;         // P rows (pitch SS)
  const size_t brow0 = (size_t)(b0 + bb) * DD + n0;  // Vt rows (pitch SS)

  f32x4 acc[8][4];
#pragma unroll
  for (int i = 0; i < 8; ++i)
#pragma unroll
    for (int j = 0; j < 4; ++j) acc[i][j] = f32x4{0.f, 0.f, 0.f, 0.f};

  mma_pipeline<SS>(P, Vt, SS, SS, arow0, brow0,
                   As, Bs, acc, wave, lane, wm, wn, col16, quad);

#pragma unroll
  for (int i = 0; i < 8; ++i)
#pragma unroll
    for (int j = 0; j < 4; ++j)
#pragma unroll
      for (int r = 0; r < 4; ++r) {
        const int gm = m0 + wm * 128 + i * 16 + quad * 4 + r;
        const int gn = n0 + wn * 64 + j * 16 + col16;
        out[((size_t)(b0 + bb) * SS + gm) * DD + gn] = acc[i][j][r];
      }
}

// ---------------------------------------------------------------------------
extern "C" void kernel_launch(void* const* d_in, const int* in_sizes, int n_in,
                              void* d_out, int out_size, void* d_ws, size_t ws_size,
                              hipStream_t stream)
{
  const float* t_out = (const float*)d_in[0];
  const float* c_out = (const float*)d_in[1];
  const float* Wq    = (const float*)d_in[2];
  const float* bq    = (const float*)d_in[3];
  const float* Wk    = (const float*)d_in[4];
  const float* bk    = (const float*)d_in[5];
  const float* Wv    = (const float*)d_in[6];
  const float* bv    = (const float*)d_in[7];
  float* out = (float*)d_out;

  // ---- sizes ----
  const size_t WELT  = (size_t)DD * DD;
  const size_t TD8   = (size_t)BB * SS * DD;             // 16.7M elems
  const size_t XH_B  = TD8 * sizeof(f16);                // 33.55 MB
  const size_t SC1_B = (size_t)SS * SS * sizeof(f16);    // 8.39 MB per batch

  // ---- pick Sc chunk c (pure function of ws_size -> graph-safe) ----
  const size_t FIXED = 3 * WELT * sizeof(f16) + 4 * XH_B;  // 140.5 MB
  int c = 2;
  for (int cand : {8, 4}) {
    size_t xsc = (size_t)cand * SC1_B;
    if (xsc < XH_B) xsc = XH_B;
    if (FIXED + xsc <= ws_size) { c = cand; break; }
  }
  size_t xsc_bytes = (size_t)c * SC1_B;
  if (xsc_bytes < XH_B) xsc_bytes = XH_B;

  // ---- layout: [W][Xh|Sc(alias)][Q][K][Vv][Vt] ----
  char* ws = (char*)d_ws;
  f16* Whq = (f16*)ws;
  f16* Whk = Whq + WELT;
  f16* Whv = Whk + WELT;
  char* XSc = (char*)(Whv + WELT);
  f16* Xh = (f16*)XSc;     // live during prep/proj
  f16* Sc = (f16*)XSc;     // live during attention chunks (aliases Xh)
  f16* Q  = (f16*)(XSc + xsc_bytes);
  f16* K  = Q  + TD8;
  f16* Vv = K  + TD8;
  f16* Vt = Vv + TD8;

  fused_prep<<<dim3(1024 + 16384), dim3(256), 0, stream>>>(
      Wq, Wk, Wv, t_out, c_out, Whq, Whk, Whv, Xh);
  proj_gemm<<<dim3(64, 4, 3), dim3(512), 0, stream>>>(
      Xh, Whq, Whk, Whv, bq, bk, bv, Q, K, Vv);
  transpose_v<<<dim3(32, 16, 8), dim3(256), 0, stream>>>(Vv, Vt);

  for (int b0 = 0; b0 < BB; b0 += c) {
    qk_gemm<<<dim3(8, 8, c), dim3(512), 0, stream>>>(Q, K, Sc, b0);
    softmax_rows<<<dim3(c * SS), dim3(256), 0, stream>>>(Sc);
    pv_gemm<<<dim3(4, 8, c), dim3(512), 0, stream>>>(Sc, Vt, out, b0);
  }
}

// Round 8
// 395.008 us; speedup vs baseline: 1.1064x; 1.0567x over previous
//
#include <hip/hip_runtime.h>
#include <cstdint>
#include <cstddef>

typedef _Float16 f16;
typedef __attribute__((ext_vector_type(4))) _Float16 f16x4;
typedef __attribute__((ext_vector_type(8))) _Float16 f16x8;
typedef __attribute__((ext_vector_type(16))) float f32x16;

#define MFMA32(a, b, c) __builtin_amdgcn_mfma_f32_32x32x16_f16((a), (b), (c), 0, 0, 0)

static constexpr int BB   = 8;
static constexpr int SS   = 2048;
static constexpr int DD   = 1024;
static constexpr int HALF = 512;
static constexpr int T32  = 256 * 32;   // f16 elems per K-tile slot (16 KB)

// async global->LDS, 16 B per lane; LDS dest is wave-uniform base + lane*16.
__device__ __forceinline__ void gll16(const f16* g, f16* lds) {
  __builtin_amdgcn_global_load_lds(
      (__attribute__((address_space(1))) void*)(g),
      (__attribute__((address_space(3))) void*)(lds), 16, 0, 0);
}

// Bijective XCD-aware block remap (nwg % 8 == 0).  qk/pv only: z-chunking
// gives each XCD one batch -> K/Vt panels L2-resident.  NOT for proj
// (natural order already co-locates A-tile consumers; R3 evidence).
__device__ __forceinline__ dim3 xcd_swz() {
  const int gx = gridDim.x, gy = gridDim.y;
  const int lin = blockIdx.x + gx * (blockIdx.y + gy * blockIdx.z);
  const int nwg = gx * gy * (int)gridDim.z;
  const int q = nwg >> 3;
  const int nlin = (lin & 7) * q + (lin >> 3);
  dim3 r;
  r.x = nlin % gx;
  const int rest = nlin / gx;
  r.y = rest % gy;
  r.z = rest / gy;
  return r;
}

// ---------------------------------------------------------------------------
// Fused prep: blocks [0,1024) convert W (fp32->fp16); blocks [1024,1024+16384)
// build Xh = concat(t_out,c_out) fp16 for ALL 8 batches.
// ---------------------------------------------------------------------------
__global__ __launch_bounds__(256) void fused_prep(
    const float* __restrict__ Wq, const float* __restrict__ Wk, const float* __restrict__ Wv,
    const float* __restrict__ t_out, const float* __restrict__ c_out,
    f16* __restrict__ Whq, f16* __restrict__ Whk, f16* __restrict__ Whv,
    f16* __restrict__ Xh)
{
  if (blockIdx.x < 1024) {
    const int i = (blockIdx.x * 256 + threadIdx.x) * 4;
    const float4 q = *(const float4*)(Wq + i);
    const float4 k = *(const float4*)(Wk + i);
    const float4 v = *(const float4*)(Wv + i);
    f16x4 a;
    a.x = (f16)q.x; a.y = (f16)q.y; a.z = (f16)q.z; a.w = (f16)q.w; *(f16x4*)(Whq + i) = a;
    a.x = (f16)k.x; a.y = (f16)k.y; a.z = (f16)k.z; a.w = (f16)k.w; *(f16x4*)(Whk + i) = a;
    a.x = (f16)v.x; a.y = (f16)v.y; a.z = (f16)v.z; a.w = (f16)v.w; *(f16x4*)(Whv + i) = a;
  } else {
    const size_t i = ((size_t)(blockIdx.x - 1024) * 256 + threadIdx.x) * 4;
    const int d = (int)(i & 1023);
    const size_t g = i >> 10;  // global token 0..16383
    const float* src = (d < HALF) ? (t_out + g * HALF + d)
                                  : (c_out + g * HALF + (d - HALF));
    const float4 x = *(const float4*)src;
    f16x4 h;
    h.x = (f16)x.x; h.y = (f16)x.y; h.z = (f16)x.z; h.w = (f16)x.w;
    *(f16x4*)(Xh + i) = h;
  }
}

// ---------------------------------------------------------------------------
// 256x256 GEMM, BK=32, 8 waves (512 thr), wave C = 128x64, 32x32x16 MFMA.
// LDS: ring of 4 K-tile slots per operand ([256 rows][32 f16], 16 KB).
// Swizzle: 16B granule g of row r lives at physical granule g ^ ((r>>1)&3);
// applied on the global SOURCE column (LDS dest linear, global_load_lds) and
// on the ds_read address.  Conflict-free for both 16-row and 32-row frag
// reads (R1-R7 measured: SQ_LDS_BANK_CONFLICT = 0; 32-row case derived).
//
// R8: 32x32x16 (half the MFMA instructions at ~15% better pipe rate; same
// LDS bytes, same acc VGPR).  Frag layouts:
//   A/B: row = lane&31, k = (lane>>5)*8 + e  (f16x8 per frag, 16B read)
//   C/D: col = lane&31, row = (reg&3) + 8*(reg>>2) + 4*(lane>>5)
// Per K-tile: 2 k-slices s=0,1; 8 MFMA per cluster; frags for cluster s=1
// read pre-entry, frags for next tile's s=0 read between clusters.
// vmcnt ledger (4 gll/wave/tile, lead 3): entry queue = [t+1(4), t+2(4)];
// vmcnt(4) retires tile t+1 (certifies next tile's reads).  Tail: t==NT-2
// -> vmcnt(0); t==NT-1 no wait.  WAR: stage->slot (t+3)&3 == (t-1)&3 after
// the entry barrier (its readers all passed it).
// VGPR rule (R4): 512 thr -> 2 waves/SIMD -> 256 cap; acc 128 + frags fits.
// ---------------------------------------------------------------------------
__device__ __forceinline__ void stage_half(
    f16* s, const f16* g, size_t r0, int ld, int k0, int u, int w4, int rr, int gg)
{
#pragma unroll
  for (int q = 0; q < 2; ++q) {
    const int rb  = u * 128 + w4 * 32 + q * 16;   // wave-uniform row block
    const int row = rb + rr;
    const int lg  = gg ^ ((row >> 1) & 3);        // pre-swizzled source granule
    gll16(g + (r0 + (size_t)row) * ld + k0 + lg * 8, s + (size_t)rb * 32);
  }
}

__device__ __forceinline__ f16x8 rdfrag(const f16* tile, int row, int lg) {
  const int phys = lg ^ ((row >> 1) & 3);
  return *(const f16x8*)&tile[row * 32 + phys * 8];
}

template <bool STAGE, int VM, bool NEXT>
__device__ __forceinline__ void tile32(
    int t, const f16* As, const f16* Bs, f16* ring,
    const f16* g_st, size_t r0_st, int ld_st,
    f32x16 (&acc)[4][2], f16x8 (&a0)[4], f16x8 (&b0)[2],
    int w4, int rr, int gg, int wm, int wn, int ln31, int kg)
{
  const f16* At = As + (t & 3) * T32;
  const f16* Bt = Bs + (t & 3) * T32;

  // pre-entry: s=1 frags of tile t (slot certified at previous barrier)
  f16x8 a1[4], b1[2];
#pragma unroll
  for (int i = 0; i < 4; ++i) a1[i] = rdfrag(At, wm * 128 + i * 32 + ln31, 2 + kg);
#pragma unroll
  for (int j = 0; j < 2; ++j) b1[j] = rdfrag(Bt, wn * 64 + j * 32 + ln31, 2 + kg);

  if constexpr (VM == 4) asm volatile("s_waitcnt vmcnt(4)" ::: "memory");
  if constexpr (VM == 0) asm volatile("s_waitcnt vmcnt(0)" ::: "memory");
  __builtin_amdgcn_s_barrier();
  __builtin_amdgcn_sched_barrier(0);

  f16* Sn = ring + ((t + 3) & 3) * T32;
  const int kn = (t + 3) * 32;
  if constexpr (STAGE) stage_half(Sn, g_st, r0_st, ld_st, kn, 0, w4, rr, gg);

  __builtin_amdgcn_s_setprio(1);
#pragma unroll
  for (int i = 0; i < 4; ++i)
#pragma unroll
    for (int j = 0; j < 2; ++j)
      acc[i][j] = MFMA32(a0[i], b0[j], acc[i][j]);
  __builtin_amdgcn_s_setprio(0);

  if constexpr (NEXT) {   // s=0 frags of tile t+1 (certified by this entry)
    const f16* At1 = As + ((t + 1) & 3) * T32;
    const f16* Bt1 = Bs + ((t + 1) & 3) * T32;
#pragma unroll
    for (int i = 0; i < 4; ++i) a0[i] = rdfrag(At1, wm * 128 + i * 32 + ln31, kg);
#pragma unroll
    for (int j = 0; j < 2; ++j) b0[j] = rdfrag(Bt1, wn * 64 + j * 32 + ln31, kg);
  }
  if constexpr (STAGE) stage_half(Sn, g_st, r0_st, ld_st, kn, 1, w4, rr, gg);

  __builtin_amdgcn_s_setprio(1);
#pragma unroll
  for (int i = 0; i < 4; ++i)
#pragma unroll
    for (int j = 0; j < 2; ++j)
      acc[i][j] = MFMA32(a1[i], b1[j], acc[i][j]);
  __builtin_amdgcn_s_setprio(0);
}

template <int K>
__device__ __forceinline__ void mma_pipeline32(
    const f16* __restrict__ A, const f16* __restrict__ B,
    int lda, int ldb, size_t arow0, size_t brow0,
    f16* As, f16* Bs, f32x16 (&acc)[4][2],
    int wave, int lane, int wm, int wn)
{
  constexpr int NT = K / 32;
  const int w4 = wave & 3, rr = lane >> 2, gg = lane & 3;
  const int ln31 = lane & 31, kg = lane >> 5;
  const f16*  g_st  = (wave < 4) ? A : B;
  const size_t r0_st = (wave < 4) ? arow0 : brow0;
  const int    ld_st = (wave < 4) ? lda : ldb;
  f16*         ring  = (wave < 4) ? As : Bs;

  // prologue: stage tiles 0,1,2 (12 gll/wave); certify tile 0.
#pragma unroll
  for (int pt = 0; pt < 3; ++pt)
#pragma unroll
    for (int u = 0; u < 2; ++u)
      stage_half(ring + pt * T32, g_st, r0_st, ld_st, pt * 32, u, w4, rr, gg);
  asm volatile("s_waitcnt vmcnt(8)" ::: "memory");
  __builtin_amdgcn_s_barrier();

  // preload tile 0 s=0 frags
  f16x8 a0[4], b0[2];
#pragma unroll
  for (int i = 0; i < 4; ++i) a0[i] = rdfrag(As, wm * 128 + i * 32 + ln31, kg);
#pragma unroll
  for (int j = 0; j < 2; ++j) b0[j] = rdfrag(Bs, wn * 64 + j * 32 + ln31, kg);

  for (int t = 0; t < NT - 3; ++t)
    tile32<true, 4, true>(t, As, Bs, ring, g_st, r0_st, ld_st, acc, a0, b0,
                          w4, rr, gg, wm, wn, ln31, kg);
  tile32<false, 4, true>(NT - 3, As, Bs, ring, g_st, r0_st, ld_st, acc, a0, b0,
                         w4, rr, gg, wm, wn, ln31, kg);
  tile32<false, 0, true>(NT - 2, As, Bs, ring, g_st, r0_st, ld_st, acc, a0, b0,
                         w4, rr, gg, wm, wn, ln31, kg);
  tile32<false, -1, false>(NT - 1, As, Bs, ring, g_st, r0_st, ld_st, acc, a0, b0,
                           w4, rr, gg, wm, wn, ln31, kg);
}

// ---------------------------------------------------------------------------
// QKV projection. grid (64, 4, 3).  z==2 writes V TRANSPOSED (Vt[b][e][s])
// via LDS bounce -- kills the separate transpose kernel + Vv buffer.
// ---------------------------------------------------------------------------
__global__ __launch_bounds__(512, 2) void proj_gemm(
    const f16* __restrict__ Xh,
    const f16* __restrict__ Whq, const f16* __restrict__ Whk, const f16* __restrict__ Whv,
    const float* __restrict__ bq, const float* __restrict__ bk, const float* __restrict__ bv,
    f16* __restrict__ Q, f16* __restrict__ K, f16* __restrict__ Vt)
{
  __shared__ alignas(16) f16 SMEM[8 * T32];
  f16* As = SMEM;
  f16* Bs = SMEM + 4 * T32;

  const int z = blockIdx.z;
  const f16* Wh = (z == 0) ? Whq : (z == 1) ? Whk : Whv;
  const float* bias = (z == 0) ? bq : (z == 1) ? bk : bv;

  const int t = threadIdx.x, lane = t & 63, wave = t >> 6;
  const int wm = wave >> 2, wn = wave & 3;
  const int ln31 = lane & 31, kg = lane >> 5;
  const int m0 = blockIdx.x * 256, n0 = blockIdx.y * 256;

  f32x16 acc[4][2];
#pragma unroll
  for (int i = 0; i < 4; ++i)
#pragma unroll
    for (int j = 0; j < 2; ++j)
#pragma unroll
      for (int r = 0; r < 16; ++r) acc[i][j][r] = 0.f;

  mma_pipeline32<DD>(Xh, Wh, DD, DD, (size_t)m0, (size_t)n0,
                     As, Bs, acc, wave, lane, wm, wn);

  if (z < 2) {
    f16* dst = (z == 0) ? Q : K;
#pragma unroll
    for (int j = 0; j < 2; ++j) {
      const int gn = n0 + wn * 64 + j * 32 + ln31;
      const float bb_ = bias[gn];
#pragma unroll
      for (int i = 0; i < 4; ++i)
#pragma unroll
        for (int r = 0; r < 16; ++r) {
          const int gm = m0 + wm * 128 + i * 32 + (r & 3) + 8 * (r >> 2) + 4 * kg;
          dst[(size_t)gm * DD + gn] = (f16)(acc[i][j][r] + bb_);
        }
    }
  } else {
    // ---- V: write Vt[b][e][s] via LDS transpose (two 128-token halves) ----
    __syncthreads();                 // all waves done with pipeline LDS
    constexpr int RL = 136;          // row pad: 16B-aligned b128 reads
    f16* tb = SMEM;                  // [256 e][RL m] = 69.6 KB
    const int bV = m0 >> 11;         // batch of this token stripe
    const int s0 = m0 & 2047;
    for (int h = 0; h < 2; ++h) {
      if (wm == h) {
#pragma unroll
        for (int j = 0; j < 2; ++j) {
          const int e = wn * 64 + j * 32 + ln31;
          const float bb_ = bias[n0 + e];
#pragma unroll
          for (int i = 0; i < 4; ++i)
#pragma unroll
            for (int g2 = 0; g2 < 4; ++g2) {
              const int m = i * 32 + g2 * 8 + 4 * kg;   // rows m..m+3
              f16x4 pk;
              pk.x = (f16)(acc[i][j][g2 * 4 + 0] + bb_);
              pk.y = (f16)(acc[i][j][g2 * 4 + 1] + bb_);
              pk.z = (f16)(acc[i][j][g2 * 4 + 2] + bb_);
              pk.w = (f16)(acc[i][j][g2 * 4 + 3] + bb_);
              *(f16x4*)&tb[e * RL + m] = pk;
            }
        }
      }
      __syncthreads();
#pragma unroll
      for (int p = 0; p < 8; ++p) {
        const int idx = p * 512 + t;
        const int e = idx >> 4, mc = idx & 15;
        const f16x8 v = *(const f16x8*)&tb[e * RL + mc * 8];
        *(f16x8*)&Vt[((size_t)bV * DD + n0 + e) * SS + s0 + h * 128 + mc * 8] = v;
      }
      __syncthreads();
    }
  }
}

// ---------------------------------------------------------------------------
// Scores, full batch: grid (8, 8, 8).
// ---------------------------------------------------------------------------
__global__ __launch_bounds__(512, 2) void qk_gemm(
    const f16* __restrict__ Q, const f16* __restrict__ K, f16* __restrict__ Sc)
{
  __shared__ alignas(16) f16 SMEM[8 * T32];
  f16* As = SMEM;
  f16* Bs = SMEM + 4 * T32;

  const dim3 bid = xcd_swz();
  const int bb = bid.z;
  const int t = threadIdx.x, lane = t & 63, wave = t >> 6;
  const int wm = wave >> 2, wn = wave & 3;
  const int ln31 = lane & 31, kg = lane >> 5;
  const int m0 = bid.y * 256, n0 = bid.x * 256;

  const size_t arow0 = (size_t)bb * SS + m0;
  const size_t brow0 = (size_t)bb * SS + n0;

  f32x16 acc[4][2];
#pragma unroll
  for (int i = 0; i < 4; ++i)
#pragma unroll
    for (int j = 0; j < 2; ++j)
#pragma unroll
      for (int r = 0; r < 16; ++r) acc[i][j][r] = 0.f;

  mma_pipeline32<DD>(Q, K, DD, DD, arow0, brow0, As, Bs, acc, wave, lane, wm, wn);

#pragma unroll
  for (int j = 0; j < 2; ++j) {
    const int gn = n0 + wn * 64 + j * 32 + ln31;
#pragma unroll
    for (int i = 0; i < 4; ++i)
#pragma unroll
      for (int r = 0; r < 16; ++r) {
        const int gm = m0 + wm * 128 + i * 32 + (r & 3) + 8 * (r >> 2) + 4 * kg;
        Sc[((size_t)bb * SS + gm) * SS + gn] = (f16)acc[i][j][r];
      }
  }
}

// ---------------------------------------------------------------------------
// Row softmax fp16 -> fp16, in place (row = 2048 f16; 256 thr x f16x8).
// ---------------------------------------------------------------------------
__global__ __launch_bounds__(256) void softmax_rows(f16* __restrict__ Sc)
{
  const size_t row = blockIdx.x;
  f16* p = Sc + row * SS;
  const int t = threadIdx.x;

  const f16x8 v = *(const f16x8*)(p + t * 8);
  float xs[8];
#pragma unroll
  for (int u = 0; u < 8; ++u) xs[u] = (float)v[u];

  float m = xs[0];
#pragma unroll
  for (int u = 1; u < 8; ++u) m = fmaxf(m, xs[u]);
#pragma unroll
  for (int off = 32; off > 0; off >>= 1) m = fmaxf(m, __shfl_xor(m, off));
  __shared__ float redm[4];
  __shared__ float reds[4];
  if ((t & 63) == 0) redm[t >> 6] = m;
  __syncthreads();
  m = fmaxf(fmaxf(redm[0], redm[1]), fmaxf(redm[2], redm[3]));

  float e[8];
  float s = 0.f;
#pragma unroll
  for (int u = 0; u < 8; ++u) {
    e[u] = expf(xs[u] - m);
    s += e[u];
  }
#pragma unroll
  for (int off = 32; off > 0; off >>= 1) s += __shfl_xor(s, off);
  if ((t & 63) == 0) reds[t >> 6] = s;
  __syncthreads();
  s = reds[0] + reds[1] + reds[2] + reds[3];
  const float inv = 1.0f / s;

  f16x8 o;
#pragma unroll
  for (int u = 0; u < 8; ++u) o[u] = (f16)(e[u] * inv);
  *(f16x8*)(p + t * 8) = o;
}

// ---------------------------------------------------------------------------
// Output, full batch: grid (4, 8, 8).  K = SS = 2048.
// ---------------------------------------------------------------------------
__global__ __launch_bounds__(512, 2) void pv_gemm(
    const f16* __restrict__ P, const f16* __restrict__ Vt, float* __restrict__ out)
{
  __shared__ alignas(16) f16 SMEM[8 * T32];
  f16* As = SMEM;
  f16* Bs = SMEM + 4 * T32;

  const dim3 bid = xcd_swz();
  const int bb = bid.z;
  const int t = threadIdx.x, lane = t & 63, wave = t >> 6;
  const int wm = wave >> 2, wn = wave & 3;
  const int ln31 = lane & 31, kg = lane >> 5;
  const int m0 = bid.y * 256;  // s
  const int n0 = bid.x * 256;  // e

  const size_t arow0 = (size_t)bb * SS + m0;   // P rows (pitch SS)
  const size_t brow0 = (size_t)bb * DD + n0;   // Vt rows (pitch SS)

  f32x16 acc[4][2];
#pragma unroll
  for (int i = 0; i < 4; ++i)
#pragma unroll
    for (int j = 0; j < 2; ++j)
#pragma unroll
      for (int r = 0; r < 16; ++r) acc[i][j][r] = 0.f;

  mma_pipeline32<SS>(P, Vt, SS, SS, arow0, brow0, As, Bs, acc, wave, lane, wm, wn);

#pragma unroll
  for (int j = 0; j < 2; ++j) {
    const int gn = n0 + wn * 64 + j * 32 + ln31;
#pragma unroll
    for (int i = 0; i < 4; ++i)
#pragma unroll
      for (int r = 0; r < 16; ++r) {
        const int gm = m0 + wm * 128 + i * 32 + (r & 3) + 8 * (r >> 2) + 4 * kg;
        out[((size_t)bb * SS + gm) * DD + gn] = acc[i][j][r];
      }
  }
}

// ---------------------------------------------------------------------------
extern "C" void kernel_launch(void* const* d_in, const int* in_sizes, int n_in,
                              void* d_out, int out_size, void* d_ws, size_t ws_size,
                              hipStream_t stream)
{
  const float* t_out = (const float*)d_in[0];
  const float* c_out = (const float*)d_in[1];
  const float* Wq    = (const float*)d_in[2];
  const float* bq    = (const float*)d_in[3];
  const float* Wk    = (const float*)d_in[4];
  const float* bk    = (const float*)d_in[5];
  const float* Wv    = (const float*)d_in[6];
  const float* bv    = (const float*)d_in[7];
  float* out = (float*)d_out;

  // ---- layout (174.0 MB total, static; Sc aliases [Xh | former-Vv]) ----
  // [Whq][Whk][Whv] 6.3MB | [ScXh 67.1MB] | [Q 33.5] | [K 33.5] | [Vt 33.5]
  const size_t WELT = (size_t)DD * DD;
  const size_t TD8  = (size_t)BB * SS * DD;        // 16.77M f16
  const size_t SCE  = (size_t)BB * SS * SS;        // 33.55M f16 (> TD8)

  char* ws = (char*)d_ws;
  f16* Whq = (f16*)ws;
  f16* Whk = Whq + WELT;
  f16* Whv = Whk + WELT;
  f16* Xh  = Whv + WELT;       // live during prep/proj
  f16* Sc  = Xh;               // live during attention (Xh dead by then)
  f16* Q   = Xh + SCE;
  f16* K   = Q + TD8;
  f16* Vt  = K + TD8;

  fused_prep<<<dim3(1024 + 16384), dim3(256), 0, stream>>>(
      Wq, Wk, Wv, t_out, c_out, Whq, Whk, Whv, Xh);
  proj_gemm<<<dim3(64, 4, 3), dim3(512), 0, stream>>>(
      Xh, Whq, Whk, Whv, bq, bk, bv, Q, K, Vt);
  qk_gemm<<<dim3(8, 8, 8), dim3(512), 0, stream>>>(Q, K, Sc);
  softmax_rows<<<dim3(BB * SS), dim3(256), 0, stream>>>(Sc);
  pv_gemm<<<dim3(4, 8, 8), dim3(512), 0, stream>>>(Sc, Vt, out);
}